// Round 13
// baseline (4088.423 us; speedup 1.0000x reference)
//
#include <hip/hip_runtime.h>

#define Tn  512
#define Bn  128
#define INn 64
#define Hn  1024

typedef __attribute__((ext_vector_type(8))) _Float16 f16x8;
typedef __attribute__((ext_vector_type(4))) float f32x4;
typedef unsigned short u16;

#define AGENT __HIP_MEMORY_SCOPE_AGENT

__device__ __forceinline__ u16 f2h(float f) {
  union { _Float16 h; u16 u; } v;
  v.h = (_Float16)f;  // v_cvt_f16_f32, RNE
  return v.u;
}
__device__ __forceinline__ float sigmoidf_(float x) {
  return 1.0f / (1.0f + __expf(-x));
}
__device__ __forceinline__ float tanhf_(float x) {
  float e = __expf(-2.0f * fabsf(x));
  float t = (1.0f - e) / (1.0f + e);
  return copysignf(t, x);
}
__device__ __forceinline__ f32x4 mfma16(f16x8 a, f16x8 b, f32x4 c) {
  return __builtin_amdgcn_mfma_f32_16x16x32_f16(a, b, c, 0, 0, 0);
}
__device__ __forceinline__ size_t hidx(int row, int col) {
  return ((size_t)((row >> 4) * 32 + (col >> 5))) * 512 +
         ((((col >> 3) & 3) * 16 + (row & 15)) * 8) + (col & 7);
}
__device__ __forceinline__ void acq_fence() {
  __builtin_amdgcn_fence(__ATOMIC_ACQUIRE, "agent");
}
// agent-coherent u32 store (sc0 sc1): writes through to LLC, leaves no dirty
// L2 line; flag stores stay RELAXED because __syncthreads() drains vmcnt(0).
__device__ __forceinline__ void coh_store(u16* p, u16 a, u16 b) {
  __hip_atomic_store((unsigned*)p, (unsigned)a | ((unsigned)b << 16),
                     __ATOMIC_RELAXED, AGENT);
}
// batch-load 4 fragments (4 kc, single f16 plane) -> all in flight before use
__device__ __forceinline__ void ldb4(f16x8 dst[4], const u16* __restrict__ h,
                                     size_t ab, int kc0) {
#pragma unroll
  for (int k = 0; k < 4; ++k)
    dst[k] = *(const f16x8*)(h + ab + (size_t)(kc0 + k) * 512);
}
__device__ __forceinline__ void fma12(f32x4 acc[3], const f16x8 b[4],
                                      const f16x8 W[3][8], int kc0) {
#pragma unroll
  for (int k = 0; k < 4; ++k) {
#pragma unroll
    for (int g = 0; g < 3; ++g)
      acc[g] = mfma16(b[k], W[g][kc0 + k], acc[g]);
  }
}

__global__ void pack_w(const float* __restrict__ s, u16* __restrict__ d, int R, int K) {
  int tid = blockIdx.x * blockDim.x + threadIdx.x;
  int total = (R * K) >> 3;
  if (tid >= total) return;
  int l = tid & 63;
  int ckc = tid >> 6;
  int nkc = K >> 5;
  int ct = ckc / nkc;
  int kc = ckc - ct * nkc;
  int row = ct * 16 + (l & 15);
  int k0 = kc * 32 + (l >> 4) * 8;
  const float* sp = s + (size_t)row * K + k0;
  float4 a = *(const float4*)sp;
  float4 b = *(const float4*)(sp + 4);
  f16x8 o;
  u16* op = (u16*)&o;
  op[0] = f2h(a.x); op[1] = f2h(a.y); op[2] = f2h(a.z); op[3] = f2h(a.w);
  op[4] = f2h(b.x); op[5] = f2h(b.y); op[6] = f2h(b.z); op[7] = f2h(b.w);
  *(f16x8*)(d + (size_t)tid * 8) = o;
}

__global__ void zero16(uint4* __restrict__ p, int n4) {
  int i = blockIdx.x * blockDim.x + threadIdx.x;
  if (i < n4) p[i] = make_uint4(0u, 0u, 0u, 0u);
}

#define PS 131072  // one packed [128][1024] f16 plane (elements)
// WO=true (write-once): ring has Tn+1 planes; h0_t lives at hA plane t+1
// (plane 0 = zeros); NO slot reuse ever -> no stale cached copy can exist ->
// NO acquire fences; consumers use normal cached loads -> same-XCD blocks
// share panels through L2 (8x broadcast absorbed). No backpressure gates.
// WO=false: round-10 behavior (depth-8 ring + per-step acq_fence) — used
// when the workspace is too small for write-once rings.
// LDS strides ODD (35/21) for bank spread. f16 operands, f32 accumulators,
// h_prev in f32 registers. Deep load batching. 1 block/CU.

template <bool WO>
__global__ __launch_bounds__(512, 1) void gru_main(
    const float* __restrict__ x,
    const float* __restrict__ b_ih0, const float* __restrict__ b_hh0,
    const float* __restrict__ b_ih1, const float* __restrict__ b_hh1,
    const float* __restrict__ b_lin,
    const u16* __restrict__ wih0p, const u16* __restrict__ whh0p,
    const u16* __restrict__ wih1p, const u16* __restrict__ whh1p,
    const u16* __restrict__ wlinp,
    u16* __restrict__ hA, u16* __restrict__ hB,
    float* __restrict__ out, int* __restrict__ flags) {
  extern __shared__ float lds[];  // 32256 floats (126 KB)
  // layer0: H[2m][4kg][3][16][35]@0 + I[2m][3][16][35]@13440 ; lin [8w][16][21]@0
  // layer1: P[4m][8w][3][16][21]@0

  const int blk  = blockIdx.x;
  const int tid  = threadIdx.x;
  const int w    = tid >> 6;
  const int lane = tid & 63;
  const int ln   = lane & 15;
  const int lq   = lane >> 4;
  const int layer = blk >> 7;
  const int lb   = blk & 127;
  const f32x4 vz = {0.f, 0.f, 0.f, 0.f};

  if (layer == 0) {
    const int bg  = lb >> 5;
    const int hsl = lb & 31;
    const int q   = w & 1;
    const int kg  = w >> 1;
    const int c16 = hsl * 2 + q;
    const bool kgl = (kg < 2);
    const int xm  = kg;  // x-gemm m-tile for kg<2 waves
    f16x8 W[3][8];
#pragma unroll
    for (int g = 0; g < 3; ++g)
#pragma unroll
      for (int kc = 0; kc < 8; ++kc)
        W[g][kc] = *(const f16x8*)(whh0p + (((size_t)(g * 64 + c16) * 32 + kg * 8 + kc) * 64 + lane) * 8);
    f16x8 Wx[3][2];
    if (kgl) {
#pragma unroll
      for (int g = 0; g < 3; ++g)
#pragma unroll
        for (int kc = 0; kc < 2; ++kc)
          Wx[g][kc] = *(const f16x8*)(wih0p + (((size_t)(g * 64 + c16) * 2 + kc) * 64 + lane) * 8);
    }
    const bool is_lin = (hsl < 8);
    const int lcg = hsl & 3;   // out col-group (16 cols)
    const int lrt = hsl >> 2;  // out row-tile (16 rows)
    float Blin = 0.f;
    f16x8 Wl[4];               // hoisted: loop-invariant lin weights
    if (is_lin) {
      Blin = b_lin[lcg * 16 + (tid & 15)];
#pragma unroll
      for (int kc = 0; kc < 4; ++kc)
        Wl[kc] = *(const f16x8*)(wlinp + (((size_t)lcg * 32 + w * 4 + kc) * 64 + lane) * 8);
    }
    const int rm  = tid >> 8;
    const int rr  = (tid >> 4) & 15;
    const int rc2 = (tid & 15) * 2;
    const int ggr = bg * 32 + rm * 16 + rr;
    float Br[2], Bz[2], Bni[2], Bnh[2];
#pragma unroll
    for (int e = 0; e < 2; ++e) {
      const int gc = hsl * 32 + rc2 + e;
      Br[e]  = b_ih0[gc] + b_hh0[gc];
      Bz[e]  = b_ih0[Hn + gc] + b_hh0[Hn + gc];
      Bni[e] = b_ih0[2 * Hn + gc];
      Bnh[e] = b_hh0[2 * Hn + gc];
    }
    const int* pPeer = flags + ((bg << 5) + (lane & 31)) * 32;
    const int* pBp   = flags + 4096 + (((bg >> 1) << 6) + lane) * 32;
    const size_t abL = ((size_t)(bg * 2 + lrt) * 32 + w * 4) * 512 + lane * 8;
    float h0prev[2] = {0.f, 0.f};  // register-carried recurrence state

    for (int t = 0; t <= Tn + 7; ++t) {
      f16x8 lbuf[4];
      if (t < Tn) {
        if (w == 0) {  // poll: peers done t-1; layer1 at t-8 (availability for
                       // lin in WO; backpressure for everyone in fence mode)
          const bool needB = WO ? (is_lin && t >= 8) : (t >= 8);
          for (;;) {
            bool ok = true;
            if (t > 0 && __hip_atomic_load(pPeer, __ATOMIC_RELAXED, AGENT) < t) ok = false;
            if (needB && __hip_atomic_load(pBp, __ATOMIC_RELAXED, AGENT) < t - 7) ok = false;
            if (!__all(ok)) { __builtin_amdgcn_s_sleep(1); continue; }
            break;
          }
          if (!WO) acq_fence();
        }
        __syncthreads();
        const u16* Ahb = hA + (size_t)(WO ? t : ((t + 7) & 7)) * PS;  // h0_{t-1}
        float4 xv0, xv1, xv2, xv3;
        if (kgl) {  // x loads first: long latency hidden behind h-gemm
          const float* xr = x + ((size_t)t * Bn + bg * 32 + xm * 16 + ln) * INn + lq * 8;
          xv0 = *(const float4*)xr;        xv1 = *(const float4*)(xr + 4);
          xv2 = *(const float4*)(xr + 32); xv3 = *(const float4*)(xr + 36);
        }
        // deep-batched GEMM: all 16 fragments + lin loads in flight before
        // the first MFMA waits
        f32x4 acc0[3] = {vz, vz, vz}, acc1[3] = {vz, vz, vz};
        f16x8 b0[4], b1[4], b2[4], b3[4];
        const size_t ab0 = ((size_t)(bg * 2 + 0) * 32 + kg * 8) * 512 + lane * 8;
        const size_t ab1 = ((size_t)(bg * 2 + 1) * 32 + kg * 8) * 512 + lane * 8;
        ldb4(b0, Ahb, ab0, 0);
        ldb4(b1, Ahb, ab0, 4);
        ldb4(b2, Ahb, ab1, 0);
        ldb4(b3, Ahb, ab1, 4);
        if (is_lin && t >= 8)  // lin operand loads (h2_{t-8}) ride the same burst
          ldb4(lbuf, hB + (size_t)(WO ? (t - 7) : ((t - 8) & 7)) * PS, abL, 0);
        fma12(acc0, b0, W, 0);
        fma12(acc0, b1, W, 4);
        fma12(acc1, b2, W, 0);
        fma12(acc1, b3, W, 4);
        {
          float* Hp0 = lds + (size_t)(0 * 4 + kg) * 1680;
          float* Hp1 = lds + (size_t)(1 * 4 + kg) * 1680;
#pragma unroll
          for (int g = 0; g < 3; ++g)
#pragma unroll
            for (int i = 0; i < 4; ++i) {
              Hp0[g * 560 + (lq * 4 + i) * 35 + q * 16 + ln] = acc0[g][i];
              Hp1[g * 560 + (lq * 4 + i) * 35 + q * 16 + ln] = acc1[g][i];
            }
        }
        if (kgl) {
          f16x8 a0, a1;
          u16* a0p = (u16*)&a0;
          u16* a1p = (u16*)&a1;
          a0p[0] = f2h(xv0.x); a0p[1] = f2h(xv0.y); a0p[2] = f2h(xv0.z); a0p[3] = f2h(xv0.w);
          a0p[4] = f2h(xv1.x); a0p[5] = f2h(xv1.y); a0p[6] = f2h(xv1.z); a0p[7] = f2h(xv1.w);
          a1p[0] = f2h(xv2.x); a1p[1] = f2h(xv2.y); a1p[2] = f2h(xv2.z); a1p[3] = f2h(xv2.w);
          a1p[4] = f2h(xv3.x); a1p[5] = f2h(xv3.y); a1p[6] = f2h(xv3.z); a1p[7] = f2h(xv3.w);
          f32x4 ax[3] = {vz, vz, vz};
#pragma unroll
          for (int g = 0; g < 3; ++g) {
            ax[g] = mfma16(a0, Wx[g][0], ax[g]);
            ax[g] = mfma16(a1, Wx[g][1], ax[g]);
          }
          float* Ip = lds + 13440 + (size_t)xm * 1680;
#pragma unroll
          for (int g = 0; g < 3; ++g)
#pragma unroll
            for (int i = 0; i < 4; ++i)
              Ip[g * 560 + (lq * 4 + i) * 35 + q * 16 + ln] = ax[g][i];
        }
        __syncthreads();
        {
          u16* whp = hA + (size_t)(WO ? (t + 1) : (t & 7)) * PS;  // h0_t
          const size_t idx0 = hidx(ggr, hsl * 32 + rc2);
          u16 hh[2];
#pragma unroll
          for (int e = 0; e < 2; ++e) {
            const int c = rc2 + e;
            const float* Ip = lds + 13440 + (size_t)rm * 1680 + rr * 35 + c;
            float I0 = Ip[0], I1 = Ip[560], I2 = Ip[1120];
            float H0 = 0.f, H1 = 0.f, H2 = 0.f;
#pragma unroll
            for (int kgi = 0; kgi < 4; ++kgi) {
              const float* Hp = lds + (size_t)(rm * 4 + kgi) * 1680 + rr * 35 + c;
              H0 += Hp[0]; H1 += Hp[560]; H2 += Hp[1120];
            }
            float r  = sigmoidf_(I0 + H0 + Br[e]);
            float zz = sigmoidf_(I1 + H1 + Bz[e]);
            float nn = tanhf_(I2 + Bni[e] + r * (H2 + Bnh[e]));
            float hv = (1.0f - zz) * nn + zz * h0prev[e];
            h0prev[e] = hv;
            hh[e] = f2h(hv);
          }
          coh_store(whp + idx0, hh[0], hh[1]);
        }
        __syncthreads();  // vmcnt(0) drained: coherent h stores visible at LLC
        if (tid == 0)
          __hip_atomic_store(flags + ((bg << 5) + hsl) * 32, t + 1, __ATOMIC_RELAXED, AGENT);
      } else if (is_lin) {
        // tail (t >= Tn): GRU phase gone; poll layer1 progress for h2_{t-8}
        if (w == 0) {
          while (!__all(__hip_atomic_load(pBp, __ATOMIC_RELAXED, AGENT) >= t - 7))
            __builtin_amdgcn_s_sleep(1);
          if (!WO) acq_fence();
        }
        __syncthreads();
        ldb4(lbuf, hB + (size_t)(WO ? (t - 7) : ((t - 8) & 7)) * PS, abL, 0);
      }
      if (is_lin && t >= 8) {
        // lin of s2 = t-8: availability (pBp >= t-7) enforced by head poll;
        // operands already in lbuf.
        const int s2 = t - 8;
        f32x4 la = vz;
#pragma unroll
        for (int k = 0; k < 4; ++k)
          la = mfma16(lbuf[k], Wl[k], la);
        __syncthreads();  // GRU-phase LDS reads done; hB loads drained (vmcnt 0)
        if (!WO && tid == 0)  // consumption signal only needed for slot reuse
          __hip_atomic_store(flags + 8192 + ((bg << 3) + hsl) * 32, s2 + 1, __ATOMIC_RELAXED, AGENT);
#pragma unroll
        for (int i = 0; i < 4; ++i)
          lds[(w * 16 + lq * 4 + i) * 21 + ln] = la[i];
        __syncthreads();
        if (tid < 256) {
          const int lr = (tid >> 4) & 15, lc = tid & 15;
          float s = Blin;
#pragma unroll
          for (int w8 = 0; w8 < 8; ++w8)
            s += lds[(w8 * 16 + lr) * 21 + lc];
          out[((size_t)s2 * Bn + bg * 32 + lrt * 16 + lr) * 64 + lcg * 16 + lc] = s;
        }
        // next iteration's head barrier orders these LDS reads vs new writes
      }
    }
  } else {
    // ---------------- layer 1: single-phase, 4 m-tiles, split-poll ----------------
    const int cs  = lb >> 1;
    const int rh  = lb & 1;
    const int side = w >> 2;
    const int ks  = w & 3;
    const u16* wsrc = side ? whh1p : wih1p;
    f16x8 W[3][8];
#pragma unroll
    for (int g = 0; g < 3; ++g)
#pragma unroll
      for (int kc = 0; kc < 8; ++kc)
        W[g][kc] = *(const f16x8*)(wsrc + (((size_t)(g * 64 + cs) * 32 + ks * 8 + kc) * 64 + lane) * 8);
    const int mq  = tid >> 7;         // elem: m-tile 0..3
    const int er  = (tid >> 3) & 15;  // elem: row in tile
    const int ec0 = (tid & 7) * 2;    // elem: col pair
    float Br2[2], Bz2[2], Bni2[2], Bnh2[2];
#pragma unroll
    for (int e = 0; e < 2; ++e) {
      const int g2 = cs * 16 + ec0 + e;
      Br2[e]  = b_ih1[g2] + b_hh1[g2];
      Bz2[e]  = b_ih1[Hn + g2] + b_hh1[Hn + g2];
      Bni2[e] = b_ih1[2 * Hn + g2];
      Bnh2[e] = b_hh1[2 * Hn + g2];
    }
    const size_t idxE = hidx(rh * 64 + mq * 16 + er, cs * 16 + ec0);
    float h1prev[2] = {0.f, 0.f};  // register-carried recurrence state
    const int* pA = flags + ((rh << 6) + lane) * 32;
    const int* pB = flags + 4096 + ((rh << 6) + lane) * 32;
    const int* pC = flags + 8192 + ((rh << 4) + (lane & 15)) * 32;

    for (int s = 0; s < Tn; ++s) {
      if (w == 0) {  // head poll: h0_s ready (+ lin consumed h2_{s-8} if reuse)
        for (;;) {
          bool ok = __hip_atomic_load(pA, __ATOMIC_RELAXED, AGENT) >= s + 1;
          if (!WO && s >= 8 && (lane & 15) == lane &&
              __hip_atomic_load(pC, __ATOMIC_RELAXED, AGENT) < s - 7) ok = false;
          if (__all(ok)) break;
          __builtin_amdgcn_s_sleep(1);
        }
        if (!WO) acq_fence();
      }
      __syncthreads();
      const u16* A1h = hA + (size_t)(WO ? (s + 1) : (s & 7)) * PS;        // h0_s
      const u16* A2h = hB + (size_t)(WO ? s : ((s + 7) & 7)) * PS;        // h1_{s-1}
      u16* whp = hB + (size_t)(WO ? (s + 1) : (s & 7)) * PS;              // h1_s
      const u16* Ahb = side ? A2h : A1h;
      // hh waves wait for peers' h1_{s-1} here; ih waves proceed immediately
      if (side && s > 0) {
        while (!__all(__hip_atomic_load(pB, __ATOMIC_RELAXED, AGENT) >= s))
          __builtin_amdgcn_s_sleep(1);
      }
      // deep-batched GEMM: 4 ldb4 groups (16 loads/lane) in flight throughout
      f32x4 acc0[3] = {vz, vz, vz}, acc1[3] = {vz, vz, vz};
      f32x4 acc2[3] = {vz, vz, vz}, acc3[3] = {vz, vz, vz};
      f16x8 b0[4], b1[4], b2[4], b3[4];
      const int mA = rh * 4;
      const size_t abT0 = ((size_t)(mA + 0) * 32 + ks * 8) * 512 + lane * 8;
      const size_t abT1 = ((size_t)(mA + 1) * 32 + ks * 8) * 512 + lane * 8;
      const size_t abT2 = ((size_t)(mA + 2) * 32 + ks * 8) * 512 + lane * 8;
      const size_t abT3 = ((size_t)(mA + 3) * 32 + ks * 8) * 512 + lane * 8;
      ldb4(b0, Ahb, abT0, 0);
      ldb4(b1, Ahb, abT0, 4);
      ldb4(b2, Ahb, abT1, 0);
      ldb4(b3, Ahb, abT1, 4);
      fma12(acc0, b0, W, 0);
      ldb4(b0, Ahb, abT2, 0);
      fma12(acc0, b1, W, 4);
      ldb4(b1, Ahb, abT2, 4);
      fma12(acc1, b2, W, 0);
      ldb4(b2, Ahb, abT3, 0);
      fma12(acc1, b3, W, 4);
      ldb4(b3, Ahb, abT3, 4);
      fma12(acc2, b0, W, 0);
      fma12(acc2, b1, W, 4);
      fma12(acc3, b2, W, 0);
      fma12(acc3, b3, W, 4);
#pragma unroll
      for (int g = 0; g < 3; ++g)
#pragma unroll
        for (int i = 0; i < 4; ++i) {
          const int ro = (lq * 4 + i) * 21 + ln;
          lds[((0 * 8 + w) * 3 + g) * 336 + ro] = acc0[g][i];
          lds[((1 * 8 + w) * 3 + g) * 336 + ro] = acc1[g][i];
          lds[((2 * 8 + w) * 3 + g) * 336 + ro] = acc2[g][i];
          lds[((3 * 8 + w) * 3 + g) * 336 + ro] = acc3[g][i];
        }
      __syncthreads();
      {  // elementwise: all 512 threads, 2 cols each
        u16 hh[2];
#pragma unroll
        for (int e = 0; e < 2; ++e) {
          const int rc = ec0 + e;
          float I0 = 0.f, I1 = 0.f, I2 = 0.f, H0 = 0.f, H1 = 0.f, H2 = 0.f;
#pragma unroll
          for (int wi = 0; wi < 4; ++wi) {
            const float* P = lds + ((mq * 8 + wi) * 3) * 336 + er * 21 + rc;
            I0 += P[0]; I1 += P[336]; I2 += P[672];
          }
#pragma unroll
          for (int wi = 4; wi < 8; ++wi) {
            const float* P = lds + ((mq * 8 + wi) * 3) * 336 + er * 21 + rc;
            H0 += P[0]; H1 += P[336]; H2 += P[672];
          }
          float r  = sigmoidf_(I0 + H0 + Br2[e]);
          float zz = sigmoidf_(I1 + H1 + Bz2[e]);
          float nn = tanhf_(I2 + Bni2[e] + r * (H2 + Bnh2[e]));
          float hv = (1.0f - zz) * nn + zz * h1prev[e];
          h1prev[e] = hv;
          hh[e] = f2h(hv);
        }
        coh_store(whp + idxE, hh[0], hh[1]);
      }
      __syncthreads();  // vmcnt(0) drained: h1 stores visible + LDS reads done
      if (tid == 0)
        __hip_atomic_store(flags + 4096 + ((rh << 6) + cs) * 32, s + 1, __ATOMIC_RELAXED, AGENT);
    }
  }
}

extern "C" void kernel_launch(void* const* d_in, const int* in_sizes, int n_in,
                              void* d_out, int out_size, void* d_ws, size_t ws_size,
                              hipStream_t stream) {
  (void)in_sizes; (void)n_in; (void)out_size;
  const float* x     = (const float*)d_in[0];
  const float* wih0f = (const float*)d_in[1];
  const float* whh0f = (const float*)d_in[2];
  const float* bih0  = (const float*)d_in[3];
  const float* bhh0  = (const float*)d_in[4];
  const float* wih1f = (const float*)d_in[5];
  const float* whh1f = (const float*)d_in[6];
  const float* bih1  = (const float*)d_in[7];
  const float* bhh1  = (const float*)d_in[8];
  const float* wlinf = (const float*)d_in[9];
  const float* blin  = (const float*)d_in[10];
  float* out = (float*)d_out;

  const size_t wbytes = (size_t)3 * 3072 * 1024 * 2 + (size_t)3072 * 64 * 2 +
                        (size_t)64 * 1024 * 2;
  const size_t woNeed = wbytes + (size_t)2 * (Tn + 1) * PS * 2 + 36864;
  bool wo = (ws_size >= woNeed);
  const int planes = wo ? (Tn + 1) : 8;

  char* w = (char*)d_ws;
  u16* whh0p = (u16*)w; w += (size_t)3072 * 1024 * 2;
  u16* wih1p = (u16*)w; w += (size_t)3072 * 1024 * 2;
  u16* whh1p = (u16*)w; w += (size_t)3072 * 1024 * 2;
  u16* wih0p = (u16*)w; w += (size_t)3072 * 64 * 2;
  u16* wlinp = (u16*)w; w += (size_t)64 * 1024 * 2;
  u16* hA    = (u16*)w; w += (size_t)planes * PS * 2;
  u16* hB    = (u16*)w; w += (size_t)planes * PS * 2;
  int* flags = (int*)w; w += 36864;

  // Raise the dyn-LDS cap for the kernel we are about to launch; if the
  // attribute call fails for the WO instantiation, fall back to fence mode.
  if (wo) {
    if (hipFuncSetAttribute((const void*)gru_main<true>,
                            hipFuncAttributeMaxDynamicSharedMemorySize,
                            131072) != hipSuccess)
      wo = false;
  }
  if (!wo) {
    (void)hipFuncSetAttribute((const void*)gru_main<false>,
                              hipFuncAttributeMaxDynamicSharedMemorySize, 131072);
  }

  const int thr = 256;
  pack_w<<<(3072 * 1024 / 8 + thr - 1) / thr, thr, 0, stream>>>(whh0f, whh0p, 3072, 1024);
  pack_w<<<(3072 * 1024 / 8 + thr - 1) / thr, thr, 0, stream>>>(wih1f, wih1p, 3072, 1024);
  pack_w<<<(3072 * 1024 / 8 + thr - 1) / thr, thr, 0, stream>>>(whh1f, whh1p, 3072, 1024);
  pack_w<<<(3072 * 64 / 8 + thr - 1) / thr, thr, 0, stream>>>(wih0f, wih0p, 3072, 64);
  pack_w<<<(64 * 1024 / 8 + thr - 1) / thr, thr, 0, stream>>>(wlinf, wlinp, 64, 1024);
  // zero: plane 0 of each ring (WO) / all 8 planes (fence mode), plus flags.
  const int zplanes = wo ? 1 : 8;
  const int nzr = zplanes * PS * 2 / 16;
  zero16<<<(nzr + thr - 1) / thr, thr, 0, stream>>>((uint4*)hA, nzr);
  zero16<<<(nzr + thr - 1) / thr, thr, 0, stream>>>((uint4*)hB, nzr);
  zero16<<<(36864 / 16 + thr - 1) / thr, thr, 0, stream>>>((uint4*)flags, 36864 / 16);

  void* args[] = {(void*)&x,     (void*)&bih0,  (void*)&bhh0,  (void*)&bih1,  (void*)&bhh1,
                  (void*)&blin,  (void*)&wih0p, (void*)&whh0p, (void*)&wih1p, (void*)&whh1p,
                  (void*)&wlinp, (void*)&hA,    (void*)&hB,    (void*)&out,   (void*)&flags};
  const void* kfn = wo ? (const void*)gru_main<true> : (const void*)gru_main<false>;
  hipLaunchCooperativeKernel(kfn, dim3(256), dim3(512), args, 129024, stream);
}

// Round 14
// 3656.767 us; speedup vs baseline: 1.1180x; 1.1180x over previous
//
#include <hip/hip_runtime.h>

#define Tn  512
#define Bn  128
#define INn 64
#define Hn  1024

typedef __attribute__((ext_vector_type(8))) _Float16 f16x8;
typedef __attribute__((ext_vector_type(4))) float f32x4;
typedef unsigned short u16;

#define AGENT __HIP_MEMORY_SCOPE_AGENT

__device__ __forceinline__ u16 f2h(float f) {
  union { _Float16 h; u16 u; } v;
  v.h = (_Float16)f;  // v_cvt_f16_f32, RNE
  return v.u;
}
__device__ __forceinline__ float sigmoidf_(float x) {
  return 1.0f / (1.0f + __expf(-x));
}
__device__ __forceinline__ float tanhf_(float x) {
  float e = __expf(-2.0f * fabsf(x));
  float t = (1.0f - e) / (1.0f + e);
  return copysignf(t, x);
}
__device__ __forceinline__ f32x4 mfma16(f16x8 a, f16x8 b, f32x4 c) {
  return __builtin_amdgcn_mfma_f32_16x16x32_f16(a, b, c, 0, 0, 0);
}
__device__ __forceinline__ size_t hidx(int row, int col) {
  return ((size_t)((row >> 4) * 32 + (col >> 5))) * 512 +
         ((((col >> 3) & 3) * 16 + (row & 15)) * 8) + (col & 7);
}
__device__ __forceinline__ void acq_fence() {
  __builtin_amdgcn_fence(__ATOMIC_ACQUIRE, "agent");
}
// agent-coherent u32 store (sc0 sc1): writes through to LLC, leaves no dirty
// L2 line; flag stores stay RELAXED because __syncthreads() drains vmcnt(0).
__device__ __forceinline__ void coh_store(u16* p, u16 a, u16 b) {
  __hip_atomic_store((unsigned*)p, (unsigned)a | ((unsigned)b << 16),
                     __ATOMIC_RELAXED, AGENT);
}
// batch-load 4 fragments (4 kc, single f16 plane) -> all in flight before use
__device__ __forceinline__ void ldb4(f16x8 dst[4], const u16* __restrict__ h,
                                     size_t ab, int kc0) {
#pragma unroll
  for (int k = 0; k < 4; ++k)
    dst[k] = *(const f16x8*)(h + ab + (size_t)(kc0 + k) * 512);
}
__device__ __forceinline__ void fma12(f32x4 acc[3], const f16x8 b[4],
                                      const f16x8 W[3][8], int kc0) {
#pragma unroll
  for (int k = 0; k < 4; ++k) {
#pragma unroll
    for (int g = 0; g < 3; ++g)
      acc[g] = mfma16(b[k], W[g][kc0 + k], acc[g]);
  }
}

__global__ void pack_w(const float* __restrict__ s, u16* __restrict__ d, int R, int K) {
  int tid = blockIdx.x * blockDim.x + threadIdx.x;
  int total = (R * K) >> 3;
  if (tid >= total) return;
  int l = tid & 63;
  int ckc = tid >> 6;
  int nkc = K >> 5;
  int ct = ckc / nkc;
  int kc = ckc - ct * nkc;
  int row = ct * 16 + (l & 15);
  int k0 = kc * 32 + (l >> 4) * 8;
  const float* sp = s + (size_t)row * K + k0;
  float4 a = *(const float4*)sp;
  float4 b = *(const float4*)(sp + 4);
  f16x8 o;
  u16* op = (u16*)&o;
  op[0] = f2h(a.x); op[1] = f2h(a.y); op[2] = f2h(a.z); op[3] = f2h(a.w);
  op[4] = f2h(b.x); op[5] = f2h(b.y); op[6] = f2h(b.z); op[7] = f2h(b.w);
  *(f16x8*)(d + (size_t)tid * 8) = o;
}

__global__ void zero16(uint4* __restrict__ p, int n4) {
  int i = blockIdx.x * blockDim.x + threadIdx.x;
  if (i < n4) p[i] = make_uint4(0u, 0u, 0u, 0u);
}

#define PS 131072  // one packed [128][1024] f16 plane (elements)
// Ring depth D (template), slot(t) = t & (D-1). Fence AMORTIZATION: the
// acquire fence only exists to kill stale clean copies of REUSED ring slots
// (staleness window = D steps, lin lag 8 < D). A fence at the step head,
// every FI <= D-?? steps, invalidates any stale line before the slot's new
// data is read (fence precedes all ring reads within the step). FI = D/2
// for margin; D=8 -> FI=1 (= per-step fencing, prior behavior).
// Backpressure gates generalize: producers overwrite slot t-D, so
// L0 needs pBp >= t-(D-1) (lin blocks additionally need pBp >= t-7 for
// h2_{t-8} availability); L1 needs pC >= s-(D-1).
// LDS strides ODD (35/21) for bank spread. f16 operands, f32 accumulators,
// h_prev in f32 registers. Deep load batching. 1 block/CU.

template <int D, int FI>
__global__ __launch_bounds__(512, 1) void gru_main(
    const float* __restrict__ x,
    const float* __restrict__ b_ih0, const float* __restrict__ b_hh0,
    const float* __restrict__ b_ih1, const float* __restrict__ b_hh1,
    const float* __restrict__ b_lin,
    const u16* __restrict__ wih0p, const u16* __restrict__ whh0p,
    const u16* __restrict__ wih1p, const u16* __restrict__ whh1p,
    const u16* __restrict__ wlinp,
    u16* __restrict__ hA, u16* __restrict__ hB,
    float* __restrict__ out, int* __restrict__ flags) {
  extern __shared__ float lds[];  // 32256 floats (126 KB)
  // layer0: H[2m][4kg][3][16][35]@0 + I[2m][3][16][35]@13440 ; lin [8w][16][21]@0
  // layer1: P[4m][8w][3][16][21]@0

  const int blk  = blockIdx.x;
  const int tid  = threadIdx.x;
  const int w    = tid >> 6;
  const int lane = tid & 63;
  const int ln   = lane & 15;
  const int lq   = lane >> 4;
  const int layer = blk >> 7;
  const int lb   = blk & 127;
  const f32x4 vz = {0.f, 0.f, 0.f, 0.f};

  if (layer == 0) {
    const int bg  = lb >> 5;
    const int hsl = lb & 31;
    const int q   = w & 1;
    const int kg  = w >> 1;
    const int c16 = hsl * 2 + q;
    const bool kgl = (kg < 2);
    const int xm  = kg;  // x-gemm m-tile for kg<2 waves
    f16x8 W[3][8];
#pragma unroll
    for (int g = 0; g < 3; ++g)
#pragma unroll
      for (int kc = 0; kc < 8; ++kc)
        W[g][kc] = *(const f16x8*)(whh0p + (((size_t)(g * 64 + c16) * 32 + kg * 8 + kc) * 64 + lane) * 8);
    f16x8 Wx[3][2];
    if (kgl) {
#pragma unroll
      for (int g = 0; g < 3; ++g)
#pragma unroll
        for (int kc = 0; kc < 2; ++kc)
          Wx[g][kc] = *(const f16x8*)(wih0p + (((size_t)(g * 64 + c16) * 2 + kc) * 64 + lane) * 8);
    }
    const bool is_lin = (hsl < 8);
    const int lcg = hsl & 3;   // out col-group (16 cols)
    const int lrt = hsl >> 2;  // out row-tile (16 rows)
    float Blin = 0.f;
    f16x8 Wl[4];               // hoisted: loop-invariant lin weights
    if (is_lin) {
      Blin = b_lin[lcg * 16 + (tid & 15)];
#pragma unroll
      for (int kc = 0; kc < 4; ++kc)
        Wl[kc] = *(const f16x8*)(wlinp + (((size_t)lcg * 32 + w * 4 + kc) * 64 + lane) * 8);
    }
    const int rm  = tid >> 8;
    const int rr  = (tid >> 4) & 15;
    const int rc2 = (tid & 15) * 2;
    const int ggr = bg * 32 + rm * 16 + rr;
    float Br[2], Bz[2], Bni[2], Bnh[2];
#pragma unroll
    for (int e = 0; e < 2; ++e) {
      const int gc = hsl * 32 + rc2 + e;
      Br[e]  = b_ih0[gc] + b_hh0[gc];
      Bz[e]  = b_ih0[Hn + gc] + b_hh0[Hn + gc];
      Bni[e] = b_ih0[2 * Hn + gc];
      Bnh[e] = b_hh0[2 * Hn + gc];
    }
    const int* pPeer = flags + ((bg << 5) + (lane & 31)) * 32;
    const int* pBp   = flags + 4096 + (((bg >> 1) << 6) + lane) * 32;
    const size_t abL = ((size_t)(bg * 2 + lrt) * 32 + w * 4) * 512 + lane * 8;
    float h0prev[2] = {0.f, 0.f};  // register-carried recurrence state

    for (int t = 0; t <= Tn + 7; ++t) {
      f16x8 lbuf[4];
      if (t < Tn) {
        if (w == 0) {  // poll: peers done t-1; layer1 gate (availability for
                       // lin h2_{t-8}, slot backpressure for everyone)
          const bool needB = (is_lin && t >= 8) || (t >= D);
          const int  thrB  = (is_lin && t >= 8) ? (t - 7) : (t - (D - 1));
          for (;;) {
            bool ok = true;
            if (t > 0 && __hip_atomic_load(pPeer, __ATOMIC_RELAXED, AGENT) < t) ok = false;
            if (needB && __hip_atomic_load(pBp, __ATOMIC_RELAXED, AGENT) < thrB) ok = false;
            if (!__all(ok)) { __builtin_amdgcn_s_sleep(1); continue; }
            break;
          }
          if ((t & (FI - 1)) == 0) acq_fence();  // amortized slot-reuse inv
        }
        __syncthreads();
        const u16* Ahb = hA + (size_t)((t + D - 1) & (D - 1)) * PS;  // h0_{t-1}
        float4 xv0, xv1, xv2, xv3;
        if (kgl) {  // x loads first: long latency hidden behind h-gemm
          const float* xr = x + ((size_t)t * Bn + bg * 32 + xm * 16 + ln) * INn + lq * 8;
          xv0 = *(const float4*)xr;        xv1 = *(const float4*)(xr + 4);
          xv2 = *(const float4*)(xr + 32); xv3 = *(const float4*)(xr + 36);
        }
        // deep-batched GEMM: all 16 fragments + lin loads in flight before
        // the first MFMA waits
        f32x4 acc0[3] = {vz, vz, vz}, acc1[3] = {vz, vz, vz};
        f16x8 b0[4], b1[4], b2[4], b3[4];
        const size_t ab0 = ((size_t)(bg * 2 + 0) * 32 + kg * 8) * 512 + lane * 8;
        const size_t ab1 = ((size_t)(bg * 2 + 1) * 32 + kg * 8) * 512 + lane * 8;
        ldb4(b0, Ahb, ab0, 0);
        ldb4(b1, Ahb, ab0, 4);
        ldb4(b2, Ahb, ab1, 0);
        ldb4(b3, Ahb, ab1, 4);
        if (is_lin && t >= 8)  // lin operand loads (h2_{t-8}) ride the same burst
          ldb4(lbuf, hB + (size_t)((t - 8) & (D - 1)) * PS, abL, 0);
        fma12(acc0, b0, W, 0);
        fma12(acc0, b1, W, 4);
        fma12(acc1, b2, W, 0);
        fma12(acc1, b3, W, 4);
        {
          float* Hp0 = lds + (size_t)(0 * 4 + kg) * 1680;
          float* Hp1 = lds + (size_t)(1 * 4 + kg) * 1680;
#pragma unroll
          for (int g = 0; g < 3; ++g)
#pragma unroll
            for (int i = 0; i < 4; ++i) {
              Hp0[g * 560 + (lq * 4 + i) * 35 + q * 16 + ln] = acc0[g][i];
              Hp1[g * 560 + (lq * 4 + i) * 35 + q * 16 + ln] = acc1[g][i];
            }
        }
        if (kgl) {
          f16x8 a0, a1;
          u16* a0p = (u16*)&a0;
          u16* a1p = (u16*)&a1;
          a0p[0] = f2h(xv0.x); a0p[1] = f2h(xv0.y); a0p[2] = f2h(xv0.z); a0p[3] = f2h(xv0.w);
          a0p[4] = f2h(xv1.x); a0p[5] = f2h(xv1.y); a0p[6] = f2h(xv1.z); a0p[7] = f2h(xv1.w);
          a1p[0] = f2h(xv2.x); a1p[1] = f2h(xv2.y); a1p[2] = f2h(xv2.z); a1p[3] = f2h(xv2.w);
          a1p[4] = f2h(xv3.x); a1p[5] = f2h(xv3.y); a1p[6] = f2h(xv3.z); a1p[7] = f2h(xv3.w);
          f32x4 ax[3] = {vz, vz, vz};
#pragma unroll
          for (int g = 0; g < 3; ++g) {
            ax[g] = mfma16(a0, Wx[g][0], ax[g]);
            ax[g] = mfma16(a1, Wx[g][1], ax[g]);
          }
          float* Ip = lds + 13440 + (size_t)xm * 1680;
#pragma unroll
          for (int g = 0; g < 3; ++g)
#pragma unroll
            for (int i = 0; i < 4; ++i)
              Ip[g * 560 + (lq * 4 + i) * 35 + q * 16 + ln] = ax[g][i];
        }
        __syncthreads();
        {
          u16* whp = hA + (size_t)(t & (D - 1)) * PS;  // h0_t
          const size_t idx0 = hidx(ggr, hsl * 32 + rc2);
          u16 hh[2];
#pragma unroll
          for (int e = 0; e < 2; ++e) {
            const int c = rc2 + e;
            const float* Ip = lds + 13440 + (size_t)rm * 1680 + rr * 35 + c;
            float I0 = Ip[0], I1 = Ip[560], I2 = Ip[1120];
            float H0 = 0.f, H1 = 0.f, H2 = 0.f;
#pragma unroll
            for (int kgi = 0; kgi < 4; ++kgi) {
              const float* Hp = lds + (size_t)(rm * 4 + kgi) * 1680 + rr * 35 + c;
              H0 += Hp[0]; H1 += Hp[560]; H2 += Hp[1120];
            }
            float r  = sigmoidf_(I0 + H0 + Br[e]);
            float zz = sigmoidf_(I1 + H1 + Bz[e]);
            float nn = tanhf_(I2 + Bni[e] + r * (H2 + Bnh[e]));
            float hv = (1.0f - zz) * nn + zz * h0prev[e];
            h0prev[e] = hv;
            hh[e] = f2h(hv);
          }
          coh_store(whp + idx0, hh[0], hh[1]);
        }
        __syncthreads();  // vmcnt(0) drained: coherent h stores visible at LLC
        if (tid == 0)
          __hip_atomic_store(flags + ((bg << 5) + hsl) * 32, t + 1, __ATOMIC_RELAXED, AGENT);
      } else if (is_lin) {
        // tail (t >= Tn): GRU phase gone; poll layer1 progress for h2_{t-8}
        if (w == 0) {
          while (!__all(__hip_atomic_load(pBp, __ATOMIC_RELAXED, AGENT) >= t - 7))
            __builtin_amdgcn_s_sleep(1);
          if ((t & (FI - 1)) == 0) acq_fence();
        }
        __syncthreads();
        ldb4(lbuf, hB + (size_t)((t - 8) & (D - 1)) * PS, abL, 0);
      }
      if (is_lin && t >= 8) {
        // lin of s2 = t-8: availability (pBp >= t-7) enforced by head poll;
        // operands already in lbuf.
        const int s2 = t - 8;
        f32x4 la = vz;
#pragma unroll
        for (int k = 0; k < 4; ++k)
          la = mfma16(lbuf[k], Wl[k], la);
        __syncthreads();  // GRU-phase LDS reads done; hB loads drained (vmcnt 0)
        if (tid == 0)  // consumption signal (slot backpressure for L1)
          __hip_atomic_store(flags + 8192 + ((bg << 3) + hsl) * 32, s2 + 1, __ATOMIC_RELAXED, AGENT);
#pragma unroll
        for (int i = 0; i < 4; ++i)
          lds[(w * 16 + lq * 4 + i) * 21 + ln] = la[i];
        __syncthreads();
        if (tid < 256) {
          const int lr = (tid >> 4) & 15, lc = tid & 15;
          float s = Blin;
#pragma unroll
          for (int w8 = 0; w8 < 8; ++w8)
            s += lds[(w8 * 16 + lr) * 21 + lc];
          out[((size_t)s2 * Bn + bg * 32 + lrt * 16 + lr) * 64 + lcg * 16 + lc] = s;
        }
        // next iteration's head barrier orders these LDS reads vs new writes
      }
    }
  } else {
    // ---------------- layer 1: single-phase, 4 m-tiles, split-poll ----------------
    const int cs  = lb >> 1;
    const int rh  = lb & 1;
    const int side = w >> 2;
    const int ks  = w & 3;
    const u16* wsrc = side ? whh1p : wih1p;
    f16x8 W[3][8];
#pragma unroll
    for (int g = 0; g < 3; ++g)
#pragma unroll
      for (int kc = 0; kc < 8; ++kc)
        W[g][kc] = *(const f16x8*)(wsrc + (((size_t)(g * 64 + cs) * 32 + ks * 8 + kc) * 64 + lane) * 8);
    const int mq  = tid >> 7;         // elem: m-tile 0..3
    const int er  = (tid >> 3) & 15;  // elem: row in tile
    const int ec0 = (tid & 7) * 2;    // elem: col pair
    float Br2[2], Bz2[2], Bni2[2], Bnh2[2];
#pragma unroll
    for (int e = 0; e < 2; ++e) {
      const int g2 = cs * 16 + ec0 + e;
      Br2[e]  = b_ih1[g2] + b_hh1[g2];
      Bz2[e]  = b_ih1[Hn + g2] + b_hh1[Hn + g2];
      Bni2[e] = b_ih1[2 * Hn + g2];
      Bnh2[e] = b_hh1[2 * Hn + g2];
    }
    const size_t idxE = hidx(rh * 64 + mq * 16 + er, cs * 16 + ec0);
    float h1prev[2] = {0.f, 0.f};  // register-carried recurrence state
    const int* pA = flags + ((rh << 6) + lane) * 32;
    const int* pB = flags + 4096 + ((rh << 6) + lane) * 32;
    const int* pC = flags + 8192 + ((rh << 4) + (lane & 15)) * 32;

    for (int s = 0; s < Tn; ++s) {
      if (w == 0) {  // head poll: h0_s ready + lin consumed h2_{s-D}
        for (;;) {
          bool ok = __hip_atomic_load(pA, __ATOMIC_RELAXED, AGENT) >= s + 1;
          if (s >= D && (lane & 15) == lane &&
              __hip_atomic_load(pC, __ATOMIC_RELAXED, AGENT) < s - (D - 1)) ok = false;
          if (__all(ok)) break;
          __builtin_amdgcn_s_sleep(1);
        }
        if ((s & (FI - 1)) == 0) acq_fence();  // amortized slot-reuse inv
      }
      __syncthreads();
      const u16* A1h = hA + (size_t)(s & (D - 1)) * PS;            // h0_s
      const u16* A2h = hB + (size_t)((s + D - 1) & (D - 1)) * PS;  // h1_{s-1}
      u16* whp = hB + (size_t)(s & (D - 1)) * PS;                  // h1_s
      const u16* Ahb = side ? A2h : A1h;
      // hh waves wait for peers' h1_{s-1} here; ih waves proceed immediately
      if (side && s > 0) {
        while (!__all(__hip_atomic_load(pB, __ATOMIC_RELAXED, AGENT) >= s))
          __builtin_amdgcn_s_sleep(1);
      }
      // deep-batched GEMM: 4 ldb4 groups (16 loads/lane) in flight throughout
      f32x4 acc0[3] = {vz, vz, vz}, acc1[3] = {vz, vz, vz};
      f32x4 acc2[3] = {vz, vz, vz}, acc3[3] = {vz, vz, vz};
      f16x8 b0[4], b1[4], b2[4], b3[4];
      const int mA = rh * 4;
      const size_t abT0 = ((size_t)(mA + 0) * 32 + ks * 8) * 512 + lane * 8;
      const size_t abT1 = ((size_t)(mA + 1) * 32 + ks * 8) * 512 + lane * 8;
      const size_t abT2 = ((size_t)(mA + 2) * 32 + ks * 8) * 512 + lane * 8;
      const size_t abT3 = ((size_t)(mA + 3) * 32 + ks * 8) * 512 + lane * 8;
      ldb4(b0, Ahb, abT0, 0);
      ldb4(b1, Ahb, abT0, 4);
      ldb4(b2, Ahb, abT1, 0);
      ldb4(b3, Ahb, abT1, 4);
      fma12(acc0, b0, W, 0);
      ldb4(b0, Ahb, abT2, 0);
      fma12(acc0, b1, W, 4);
      ldb4(b1, Ahb, abT2, 4);
      fma12(acc1, b2, W, 0);
      ldb4(b2, Ahb, abT3, 0);
      fma12(acc1, b3, W, 4);
      ldb4(b3, Ahb, abT3, 4);
      fma12(acc2, b0, W, 0);
      fma12(acc2, b1, W, 4);
      fma12(acc3, b2, W, 0);
      fma12(acc3, b3, W, 4);
#pragma unroll
      for (int g = 0; g < 3; ++g)
#pragma unroll
        for (int i = 0; i < 4; ++i) {
          const int ro = (lq * 4 + i) * 21 + ln;
          lds[((0 * 8 + w) * 3 + g) * 336 + ro] = acc0[g][i];
          lds[((1 * 8 + w) * 3 + g) * 336 + ro] = acc1[g][i];
          lds[((2 * 8 + w) * 3 + g) * 336 + ro] = acc2[g][i];
          lds[((3 * 8 + w) * 3 + g) * 336 + ro] = acc3[g][i];
        }
      __syncthreads();
      {  // elementwise: all 512 threads, 2 cols each
        u16 hh[2];
#pragma unroll
        for (int e = 0; e < 2; ++e) {
          const int rc = ec0 + e;
          float I0 = 0.f, I1 = 0.f, I2 = 0.f, H0 = 0.f, H1 = 0.f, H2 = 0.f;
#pragma unroll
          for (int wi = 0; wi < 4; ++wi) {
            const float* P = lds + ((mq * 8 + wi) * 3) * 336 + er * 21 + rc;
            I0 += P[0]; I1 += P[336]; I2 += P[672];
          }
#pragma unroll
          for (int wi = 4; wi < 8; ++wi) {
            const float* P = lds + ((mq * 8 + wi) * 3) * 336 + er * 21 + rc;
            H0 += P[0]; H1 += P[336]; H2 += P[672];
          }
          float r  = sigmoidf_(I0 + H0 + Br2[e]);
          float zz = sigmoidf_(I1 + H1 + Bz2[e]);
          float nn = tanhf_(I2 + Bni2[e] + r * (H2 + Bnh2[e]));
          float hv = (1.0f - zz) * nn + zz * h1prev[e];
          h1prev[e] = hv;
          hh[e] = f2h(hv);
        }
        coh_store(whp + idxE, hh[0], hh[1]);
      }
      __syncthreads();  // vmcnt(0) drained: h1 stores visible + LDS reads done
      if (tid == 0)
        __hip_atomic_store(flags + 4096 + ((rh << 6) + cs) * 32, s + 1, __ATOMIC_RELAXED, AGENT);
    }
  }
}

extern "C" void kernel_launch(void* const* d_in, const int* in_sizes, int n_in,
                              void* d_out, int out_size, void* d_ws, size_t ws_size,
                              hipStream_t stream) {
  (void)in_sizes; (void)n_in; (void)out_size;
  const float* x     = (const float*)d_in[0];
  const float* wih0f = (const float*)d_in[1];
  const float* whh0f = (const float*)d_in[2];
  const float* bih0  = (const float*)d_in[3];
  const float* bhh0  = (const float*)d_in[4];
  const float* wih1f = (const float*)d_in[5];
  const float* whh1f = (const float*)d_in[6];
  const float* bih1  = (const float*)d_in[7];
  const float* bhh1  = (const float*)d_in[8];
  const float* wlinf = (const float*)d_in[9];
  const float* blin  = (const float*)d_in[10];
  float* out = (float*)d_out;

  const size_t wbytes = (size_t)3 * 3072 * 1024 * 2 + (size_t)3072 * 64 * 2 +
                        (size_t)64 * 1024 * 2;
  const size_t need64 = wbytes + (size_t)2 * 64 * PS * 2 + 36864;
  const size_t need16 = wbytes + (size_t)2 * 16 * PS * 2 + 36864;
  const int D = (ws_size >= need64) ? 64 : (ws_size >= need16 ? 16 : 8);

  char* w = (char*)d_ws;
  u16* whh0p = (u16*)w; w += (size_t)3072 * 1024 * 2;
  u16* wih1p = (u16*)w; w += (size_t)3072 * 1024 * 2;
  u16* whh1p = (u16*)w; w += (size_t)3072 * 1024 * 2;
  u16* wih0p = (u16*)w; w += (size_t)3072 * 64 * 2;
  u16* wlinp = (u16*)w; w += (size_t)64 * 1024 * 2;
  u16* hA    = (u16*)w; w += (size_t)D * PS * 2;
  u16* hB    = (u16*)w; w += (size_t)D * PS * 2;
  int* flags = (int*)w; w += 36864;

  const void* kfn = (D == 64) ? (const void*)gru_main<64, 32>
                  : (D == 16) ? (const void*)gru_main<16, 8>
                              : (const void*)gru_main<8, 1>;
  (void)hipFuncSetAttribute(kfn, hipFuncAttributeMaxDynamicSharedMemorySize, 131072);

  const int thr = 256;
  pack_w<<<(3072 * 1024 / 8 + thr - 1) / thr, thr, 0, stream>>>(whh0f, whh0p, 3072, 1024);
  pack_w<<<(3072 * 1024 / 8 + thr - 1) / thr, thr, 0, stream>>>(wih1f, wih1p, 3072, 1024);
  pack_w<<<(3072 * 1024 / 8 + thr - 1) / thr, thr, 0, stream>>>(whh1f, whh1p, 3072, 1024);
  pack_w<<<(3072 * 64 / 8 + thr - 1) / thr, thr, 0, stream>>>(wih0f, wih0p, 3072, 64);
  pack_w<<<(64 * 1024 / 8 + thr - 1) / thr, thr, 0, stream>>>(wlinf, wlinp, 64, 1024);
  // zero all D planes of both rings (slot D-1 is read as h_{-1}=0 at t=0) + flags
  const int nzr = D * PS * 2 / 16;
  zero16<<<(nzr + thr - 1) / thr, thr, 0, stream>>>((uint4*)hA, nzr);
  zero16<<<(nzr + thr - 1) / thr, thr, 0, stream>>>((uint4*)hB, nzr);
  zero16<<<(36864 / 16 + thr - 1) / thr, thr, 0, stream>>>((uint4*)flags, 36864 / 16);

  void* args[] = {(void*)&x,     (void*)&bih0,  (void*)&bhh0,  (void*)&bih1,  (void*)&bhh1,
                  (void*)&blin,  (void*)&wih0p, (void*)&whh0p, (void*)&wih1p, (void*)&whh1p,
                  (void*)&wlinp, (void*)&hA,    (void*)&hB,    (void*)&out,   (void*)&flags};
  hipLaunchCooperativeKernel(kfn, dim3(256), dim3(512), args, 129024, stream);
}